// Round 6
// baseline (271.352 us; speedup 1.0000x reference)
//
#include <hip/hip_runtime.h>
#include <hip/hip_bf16.h>

typedef short short8 __attribute__((ext_vector_type(8)));
typedef float f32x4 __attribute__((ext_vector_type(4)));

#define EPSF 1e-8f
#define NROWS 16384  // total hat rows (2048 rows * 8 chunks)

__device__ __forceinline__ unsigned short f2bf(float f) {
  __hip_bfloat16 h = __float2bfloat16(f);
  return *reinterpret_cast<unsigned short*>(&h);
}

// DPP mov with old=undef -> GCNDPPCombine can fuse into the consuming VALU op.
template <int CTRL>
__device__ __forceinline__ float dmov(float x) {
  return __builtin_bit_cast(
      float, __builtin_amdgcn_mov_dpp(__builtin_bit_cast(int, x), CTRL, 0xF, 0xF, false));
}
#define DPP_XOR1 0xB1   // quad_perm(1,0,3,2)
#define DPP_XOR2 0x4E   // quad_perm(2,3,0,1)
#define DPP_P4 0x12C    // row_ror:12 -> lane i gets lane (i+4)&15

// lane ^ 16 via ds_swizzle BitMode (and=0x1F, xor=16)
__device__ __forceinline__ float swz16(float x) {
  return __builtin_bit_cast(
      float, __builtin_amdgcn_ds_swizzle(__builtin_bit_cast(int, x), 0x401F));
}

// ---------------------------------------------------------------------------
// prep: one WAVE per row, 16 elems per lane, no barriers, no LDS.
// K-major store of Ahat/Bhat: byte addr = (slot*NROWS + hatrow)*16,
// slot = 16B-of-K within the row's 128-chunk (0..15).
// Factors interleaved: f[(row*4+v)*2 + {e,o}] = n128/n256.
// ---------------------------------------------------------------------------
__global__ __launch_bounds__(256) void prep_kernel(
    const float* __restrict__ img, const float* __restrict__ cap,
    unsigned short* __restrict__ Ahat, unsigned short* __restrict__ Bhat,
    float* __restrict__ fa, float* __restrict__ fb)
{
  int tid = threadIdx.x;
  int l = tid & 63;
  int w = tid >> 6;
  int rowid = blockIdx.x * 4 + w;      // 0..4095
  int isCap = rowid >> 11;
  int row = rowid & 2047;
  const float* src = (isCap ? cap : img) + (size_t)row * 1024;
  unsigned short* dstHat = isCap ? Bhat : Ahat;

  // lane owns elements [l*16, l*16+16) -> 2 slots of chunk j = l>>3
  float4 v0 = reinterpret_cast<const float4*>(src)[l * 4 + 0];
  float4 v1 = reinterpret_cast<const float4*>(src)[l * 4 + 1];
  float4 v2 = reinterpret_cast<const float4*>(src)[l * 4 + 2];
  float4 v3 = reinterpret_cast<const float4*>(src)[l * 4 + 3];

  float ss = v0.x*v0.x + v0.y*v0.y + v0.z*v0.z + v0.w*v0.w
           + v1.x*v1.x + v1.y*v1.y + v1.z*v1.z + v1.w*v1.w
           + v2.x*v2.x + v2.y*v2.y + v2.z*v2.z + v2.w*v2.w
           + v3.x*v3.x + v3.y*v3.y + v3.z*v3.z + v3.w*v3.w;
  ss += __shfl_xor(ss, 1);
  ss += __shfl_xor(ss, 2);
  ss += __shfl_xor(ss, 4);
  float s128 = ss;                               // chunk sumsq (8-lane group)
  float s256 = s128 + __shfl_xor(s128, 8);       // 256-chunk sumsq
  float s512 = s256 + __shfl_xor(s256, 16);
  float rowsum = s512 + __shfl_xor(s512, 32);    // full-row sumsq
  float rn = sqrtf(rowsum) + EPSF;               // global caption row norm

  // img:  x / (sqrt(s128)+eps);   cap: x / (sqrt(s128) + eps*rn)
  float scale;
  if (isCap) scale = 1.0f / (sqrtf(s128) + EPSF * rn);
  else       scale = 1.0f / (sqrtf(s128) + EPSF);

  unsigned int p0 = (unsigned)f2bf(v0.x*scale) | ((unsigned)f2bf(v0.y*scale) << 16);
  unsigned int p1 = (unsigned)f2bf(v0.z*scale) | ((unsigned)f2bf(v0.w*scale) << 16);
  unsigned int p2 = (unsigned)f2bf(v1.x*scale) | ((unsigned)f2bf(v1.y*scale) << 16);
  unsigned int p3 = (unsigned)f2bf(v1.z*scale) | ((unsigned)f2bf(v1.w*scale) << 16);
  unsigned int p4 = (unsigned)f2bf(v2.x*scale) | ((unsigned)f2bf(v2.y*scale) << 16);
  unsigned int p5 = (unsigned)f2bf(v2.z*scale) | ((unsigned)f2bf(v2.w*scale) << 16);
  unsigned int p6 = (unsigned)f2bf(v3.x*scale) | ((unsigned)f2bf(v3.y*scale) << 16);
  unsigned int p7 = (unsigned)f2bf(v3.z*scale) | ((unsigned)f2bf(v3.w*scale) << 16);

  int rh = row * 8 + (l >> 3);       // hat row
  int s0 = (l & 7) * 2;              // first 16B k-slot
  char* base = (char*)dstHat + ((size_t)s0 * NROWS + rh) * 16;
  *reinterpret_cast<uint4*>(base) = make_uint4(p0, p1, p2, p3);
  *reinterpret_cast<uint4*>(base + (size_t)NROWS * 16) = make_uint4(p4, p5, p6, p7);

  int l15 = l & 15;
  if (l15 == 0 || l15 == 8) {
    float n128, n256;
    if (isCap) { n128 = sqrtf(s128) / rn + EPSF; n256 = sqrtf(s256) / rn + EPSF; }
    else       { n128 = sqrtf(s128) + EPSF;      n256 = sqrtf(s256) + EPSF; }
    float f = n128 / n256;
    int v256 = l >> 4;
    float* dst = isCap ? fb : fa;
    dst[(row * 4 + v256) * 2 + (l15 >> 3)] = f;
  }
}

// ---------------------------------------------------------------------------
// sims: 128x256 hat tile per block, 4 waves side-by-side (each 128x64,
// FM=8 x FN=4 fragments, K=128).  Fragments loaded directly from K-major
// global (contiguous 256B per 16-lane group).  Fused DPP epilogue; 2KB LDS
// for output staging.  C layout: col=lane&15, row=(lane>>4)*4+reg.
// ---------------------------------------------------------------------------
__global__ __launch_bounds__(256, 2) void sims_kernel(
    const unsigned short* __restrict__ Ahat, const unsigned short* __restrict__ Bhat,
    const float* __restrict__ fa, const float* __restrict__ fb,
    float* __restrict__ out)
{
  __shared__ float outLds[512];
  int tid = threadIdx.x;
  int lane = tid & 63;
  int w = tid >> 6;

  // XCD-partitioned: XCD x owns tn strip [8x, 8x+8); 8 consecutive blocks
  // within an XCD share tm (A-panel L2 reuse).  Bijective (8192 blocks).
  int bx = blockIdx.x;
  int x = bx & 7;
  int l = bx >> 3;            // 0..1023
  int tm = l >> 3;            // 0..127
  int tn = (x << 3) | (l & 7);  // 0..63
  int m0 = tm * 128;
  int n0 = tn * 256;

  int wc = w * 64;            // wave's hat-col offset in tile
  int rl = lane & 15;
  int g = lane >> 4;

  unsigned vA = (unsigned)g * (NROWS * 16u) + (unsigned)(m0 + rl) * 16u;
  unsigned vB = (unsigned)g * (NROWS * 16u) + (unsigned)(n0 + wc + rl) * 16u;
  const char* Abase = (const char*)Ahat;
  const char* Bbase = (const char*)Bhat;

  // caption-side factors (interleaved e,o)
  float2 fbv[4];
  int colBase = n0 + wc + rl;
#pragma unroll
  for (int fn = 0; fn < 4; ++fn)
    fbv[fn] = *reinterpret_cast<const float2*>(fb + ((colBase + fn * 16) >> 1) * 2);

  f32x4 acc[8][4] = {};

#pragma unroll
  for (int kt = 0; kt < 4; ++kt) {
    const char* Ak = Abase + (size_t)kt * (4u * NROWS * 16u);
    const char* Bk = Bbase + (size_t)kt * (4u * NROWS * 16u);
    short8 av[8], bv[4];
#pragma unroll
    for (int f = 0; f < 8; ++f)
      av[f] = *reinterpret_cast<const short8*>(Ak + vA + f * 256);
#pragma unroll
    for (int f = 0; f < 4; ++f)
      bv[f] = *reinterpret_cast<const short8*>(Bk + vB + f * 256);
#pragma unroll
    for (int fm = 0; fm < 8; ++fm)
#pragma unroll
      for (int fn = 0; fn < 4; ++fn)
        acc[fm][fn] = __builtin_amdgcn_mfma_f32_16x16x32_bf16(av[fm], bv[fn], acc[fm][fn], 0, 0, 0);
  }

  bool writer = ((lane & 7) == 0) && ((g & 1) == 0);
  int pBase = (g >> 1) * 32 + (wc >> 3) + (rl >> 3);  // pi*32 + pj base

#pragma unroll
  for (int fm = 0; fm < 8; ++fm) {
    int vi = (m0 + fm * 16 + 4 * g) >> 1;  // even
    float4 fav = *reinterpret_cast<const float4*>(fa + vi * 2);  // e0,o0,e1,o1
#pragma unroll
    for (int fn = 0; fn < 4; ++fn) {
      f32x4 a = acc[fm][fn];

      // 128-path: max over this img row's 8 hat rows (per col), pair-sum cols
      float mm = fmaxf(fmaxf(a[0], a[1]), fmaxf(a[2], a[3]));
      float m8 = fmaxf(mm, swz16(mm));
      float u = m8 + dmov<DPP_XOR1>(m8);

      // 256-path: Q = fe*P[2v][2t] + fo*P[2v+1][2t+1]
      float s1 = dmov<DPP_XOR1>(a[1]);
      float s3 = dmov<DPP_XOR1>(a[3]);
      float qa = a[0] * (fav.x * fbv[fn].x) + s1 * (fav.y * fbv[fn].y);
      float qb = a[2] * (fav.z * fbv[fn].x) + s3 * (fav.w * fbv[fn].y);
      float qm = fmaxf(qa, qb);
      qm = fmaxf(qm, swz16(qm));

      // merged tree: Y + Z
      float wv = u + qm;
      wv += dmov<DPP_XOR2>(wv);
      wv += dmov<DPP_P4>(wv);

      if (writer) outLds[pBase + fm * 64 + fn * 2] = wv;  // (fm*2+g/2)*32 + pj
    }
  }

  __syncthreads();
#pragma unroll
  for (int i = 0; i < 2; ++i) {
    int idx = tid + i * 256;
    int pr = idx >> 5, pc = idx & 31;
    out[(size_t)(tm * 16 + pr) * 2048 + (tn * 32 + pc)] = outLds[idx];
  }
}

// ---------------------------------------------------------------------------
extern "C" void kernel_launch(void* const* d_in, const int* in_sizes, int n_in,
                              void* d_out, int out_size, void* d_ws, size_t ws_size,
                              hipStream_t stream) {
  const float* img = (const float*)d_in[0];
  const float* cap = (const float*)d_in[1];
  float* out = (float*)d_out;

  char* ws = (char*)d_ws;
  unsigned short* Ahat = (unsigned short*)ws;                              // 4 MB, K-major
  unsigned short* Bhat = (unsigned short*)(ws + (size_t)4 * 1024 * 1024);  // 4 MB, K-major
  float* fa = (float*)(ws + (size_t)8 * 1024 * 1024);  // 2048*4 pairs (e,o)
  float* fb = fa + 2048 * 4 * 2;

  prep_kernel<<<1024, 256, 0, stream>>>(img, cap, Ahat, Bhat, fa, fb);
  sims_kernel<<<8192, 256, 0, stream>>>(Ahat, Bhat, fa, fb, out);
}

// Round 7
// 169.802 us; speedup vs baseline: 1.5981x; 1.5981x over previous
//
#include <hip/hip_runtime.h>
#include <hip/hip_bf16.h>

typedef short short8 __attribute__((ext_vector_type(8)));
typedef float f32x4 __attribute__((ext_vector_type(4)));

#define EPSF 1e-8f
#define NROWS 16384  // total hat rows (2048 rows * 8 chunks)

__device__ __forceinline__ unsigned short f2bf(float f) {
  __hip_bfloat16 h = __float2bfloat16(f);
  return *reinterpret_cast<unsigned short*>(&h);
}

// DPP mov with old=undef -> GCNDPPCombine can fuse into the consuming VALU op.
template <int CTRL>
__device__ __forceinline__ float dmov(float x) {
  return __builtin_bit_cast(
      float, __builtin_amdgcn_mov_dpp(__builtin_bit_cast(int, x), CTRL, 0xF, 0xF, false));
}
#define DPP_XOR1 0xB1   // quad_perm(1,0,3,2)
#define DPP_XOR2 0x4E   // quad_perm(2,3,0,1)
#define DPP_P4 0x12C    // row_ror:12 -> lane i gets lane (i+4)&15

// lane ^ 16 via ds_swizzle BitMode (and=0x1F, xor=16)
__device__ __forceinline__ float swz16(float x) {
  return __builtin_bit_cast(
      float, __builtin_amdgcn_ds_swizzle(__builtin_bit_cast(int, x), 0x401F));
}

// ---------------------------------------------------------------------------
// prep: one WAVE per row, 16 elems per lane, no barriers, no LDS.
// K-major store of Ahat/Bhat: byte addr = (slot*NROWS + hatrow)*16.
// Factors interleaved: f[(row*4+v)*2 + {e,o}] = n128/n256.
// ---------------------------------------------------------------------------
__global__ __launch_bounds__(256) void prep_kernel(
    const float* __restrict__ img, const float* __restrict__ cap,
    unsigned short* __restrict__ Ahat, unsigned short* __restrict__ Bhat,
    float* __restrict__ fa, float* __restrict__ fb)
{
  int tid = threadIdx.x;
  int l = tid & 63;
  int w = tid >> 6;
  int rowid = blockIdx.x * 4 + w;      // 0..4095
  int isCap = rowid >> 11;
  int row = rowid & 2047;
  const float* src = (isCap ? cap : img) + (size_t)row * 1024;
  unsigned short* dstHat = isCap ? Bhat : Ahat;

  float4 v0 = reinterpret_cast<const float4*>(src)[l * 4 + 0];
  float4 v1 = reinterpret_cast<const float4*>(src)[l * 4 + 1];
  float4 v2 = reinterpret_cast<const float4*>(src)[l * 4 + 2];
  float4 v3 = reinterpret_cast<const float4*>(src)[l * 4 + 3];

  float ss = v0.x*v0.x + v0.y*v0.y + v0.z*v0.z + v0.w*v0.w
           + v1.x*v1.x + v1.y*v1.y + v1.z*v1.z + v1.w*v1.w
           + v2.x*v2.x + v2.y*v2.y + v2.z*v2.z + v2.w*v2.w
           + v3.x*v3.x + v3.y*v3.y + v3.z*v3.z + v3.w*v3.w;
  ss += __shfl_xor(ss, 1);
  ss += __shfl_xor(ss, 2);
  ss += __shfl_xor(ss, 4);
  float s128 = ss;                               // chunk sumsq (8-lane group)
  float s256 = s128 + __shfl_xor(s128, 8);       // 256-chunk sumsq
  float s512 = s256 + __shfl_xor(s256, 16);
  float rowsum = s512 + __shfl_xor(s512, 32);    // full-row sumsq
  float rn = sqrtf(rowsum) + EPSF;               // global caption row norm

  // img:  x / (sqrt(s128)+eps);   cap: x / (sqrt(s128) + eps*rn)
  float scale;
  if (isCap) scale = 1.0f / (sqrtf(s128) + EPSF * rn);
  else       scale = 1.0f / (sqrtf(s128) + EPSF);

  unsigned int p0 = (unsigned)f2bf(v0.x*scale) | ((unsigned)f2bf(v0.y*scale) << 16);
  unsigned int p1 = (unsigned)f2bf(v0.z*scale) | ((unsigned)f2bf(v0.w*scale) << 16);
  unsigned int p2 = (unsigned)f2bf(v1.x*scale) | ((unsigned)f2bf(v1.y*scale) << 16);
  unsigned int p3 = (unsigned)f2bf(v1.z*scale) | ((unsigned)f2bf(v1.w*scale) << 16);
  unsigned int p4 = (unsigned)f2bf(v2.x*scale) | ((unsigned)f2bf(v2.y*scale) << 16);
  unsigned int p5 = (unsigned)f2bf(v2.z*scale) | ((unsigned)f2bf(v2.w*scale) << 16);
  unsigned int p6 = (unsigned)f2bf(v3.x*scale) | ((unsigned)f2bf(v3.y*scale) << 16);
  unsigned int p7 = (unsigned)f2bf(v3.z*scale) | ((unsigned)f2bf(v3.w*scale) << 16);

  int rh = row * 8 + (l >> 3);       // hat row
  int s0 = (l & 7) * 2;              // first 16B k-slot
  char* base = (char*)dstHat + ((size_t)s0 * NROWS + rh) * 16;
  *reinterpret_cast<uint4*>(base) = make_uint4(p0, p1, p2, p3);
  *reinterpret_cast<uint4*>(base + (size_t)NROWS * 16) = make_uint4(p4, p5, p6, p7);

  int l15 = l & 15;
  if (l15 == 0 || l15 == 8) {
    float n128, n256;
    if (isCap) { n128 = sqrtf(s128) / rn + EPSF; n256 = sqrtf(s256) / rn + EPSF; }
    else       { n128 = sqrtf(s128) + EPSF;      n256 = sqrtf(s256) + EPSF; }
    float f = n128 / n256;
    int v256 = l >> 4;
    float* dst = isCap ? fb : fa;
    dst[(row * 4 + v256) * 2 + (l15 >> 3)] = f;
  }
}

// ---------------------------------------------------------------------------
// sims: 128x128 hat tile per block, 4 waves (each 64x64, FM=4 x FN=4, K=128),
// fragments loaded directly from K-major global (contiguous 256B per 16-lane
// group) with a 2-deep REGISTER DOUBLE-BUFFER pipeline (loads for kt+1 issue
// before kt's MFMAs).  Fused DPP epilogue; 1KB LDS for output staging.
// C layout: col=lane&15, row=(lane>>4)*4+reg.
// ---------------------------------------------------------------------------
__global__ __launch_bounds__(256, 3) void sims_kernel(
    const unsigned short* __restrict__ Ahat, const unsigned short* __restrict__ Bhat,
    const float* __restrict__ fa, const float* __restrict__ fb,
    float* __restrict__ out)
{
  __shared__ float outLds[256];
  int tid = threadIdx.x;
  int lane = tid & 63;
  int w = tid >> 6;

  // XCD-partitioned: XCD x owns tn strip [16x,16x+16); 16 consecutive blocks
  // within an XCD share tm (A-panel L2 reuse).  Bijective (16384 blocks).
  int bx = blockIdx.x;
  int x = bx & 7;
  int l = bx >> 3;              // 0..2047
  int tm = l >> 4;              // 0..127
  int tn = (x << 4) | (l & 15); // 0..127
  int m0 = tm * 128;
  int n0 = tn * 128;

  int wr = (w >> 1) * 64;
  int wc = (w & 1) * 64;
  int rl = lane & 15;
  int g = lane >> 4;

  unsigned vA = (unsigned)g * (NROWS * 16u) + (unsigned)(m0 + wr + rl) * 16u;
  unsigned vB = (unsigned)g * (NROWS * 16u) + (unsigned)(n0 + wc + rl) * 16u;
  const char* Abase = (const char*)Ahat;
  const char* Bbase = (const char*)Bhat;
  const unsigned kstep = 4u * NROWS * 16u;  // bytes per kt group

  // caption-side factors (interleaved e,o): in flight during the K-loop
  float2 fbv[4];
  int colBase = n0 + wc + rl;
#pragma unroll
  for (int fn = 0; fn < 4; ++fn)
    fbv[fn] = *reinterpret_cast<const float2*>(fb + ((colBase + fn * 16) >> 1) * 2);

  // img-side factors: one float4 (e0,o0,e1,o1) per fm, prefetched early
  int viBase = (m0 + wr + 4 * g) >> 1;
  float4 favv[4];

  short8 av0[4], bv0[4], av1[4], bv1[4];

#define LOADF(AV, BV, KT)                                                        \
  {                                                                              \
    const char* Ak = Abase + (unsigned)(KT) * kstep;                             \
    const char* Bk = Bbase + (unsigned)(KT) * kstep;                             \
    _Pragma("unroll") for (int f = 0; f < 4; ++f)                                \
        AV[f] = *reinterpret_cast<const short8*>(Ak + vA + f * 256);             \
    _Pragma("unroll") for (int f = 0; f < 4; ++f)                                \
        BV[f] = *reinterpret_cast<const short8*>(Bk + vB + f * 256);             \
  }

#define MFMAS(AV, BV)                                                            \
  _Pragma("unroll") for (int fm = 0; fm < 4; ++fm)                               \
      _Pragma("unroll") for (int fn = 0; fn < 4; ++fn)                           \
          acc[fm][fn] = __builtin_amdgcn_mfma_f32_16x16x32_bf16(                 \
              AV[fm], BV[fn], acc[fm][fn], 0, 0, 0);

  f32x4 acc[4][4] = {};

  LOADF(av0, bv0, 0);
  LOADF(av1, bv1, 1);
#pragma unroll
  for (int fm = 0; fm < 4; ++fm)
    favv[fm] = *reinterpret_cast<const float4*>(fa + (viBase + fm * 8) * 2);
  MFMAS(av0, bv0);
  LOADF(av0, bv0, 2);
  MFMAS(av1, bv1);
  LOADF(av1, bv1, 3);
  MFMAS(av0, bv0);
  MFMAS(av1, bv1);

#undef LOADF
#undef MFMAS

  bool writer = ((lane & 7) == 0) && ((g & 1) == 0);
  int pBase = ((wr >> 3) + (g >> 1)) * 16 + (wc >> 3) + (rl >> 3);

#pragma unroll
  for (int fm = 0; fm < 4; ++fm) {
    float4 fav = favv[fm];  // e0,o0,e1,o1 for rows fm*16+4g(+1..3)
#pragma unroll
    for (int fn = 0; fn < 4; ++fn) {
      f32x4 a = acc[fm][fn];

      // 128-path: max over this img row's 8 hat rows (per col), pair-sum cols
      float mm = fmaxf(fmaxf(a[0], a[1]), fmaxf(a[2], a[3]));
      float m8 = fmaxf(mm, swz16(mm));
      float u = m8 + dmov<DPP_XOR1>(m8);

      // 256-path: Q = fe*P[2v][2t] + fo*P[2v+1][2t+1]
      float s1 = dmov<DPP_XOR1>(a[1]);
      float s3 = dmov<DPP_XOR1>(a[3]);
      float qa = a[0] * (fav.x * fbv[fn].x) + s1 * (fav.y * fbv[fn].y);
      float qb = a[2] * (fav.z * fbv[fn].x) + s3 * (fav.w * fbv[fn].y);
      float qm = fmaxf(qa, qb);
      qm = fmaxf(qm, swz16(qm));

      // merged tree: Y + Z
      float wv = u + qm;
      wv += dmov<DPP_XOR2>(wv);
      wv += dmov<DPP_P4>(wv);

      if (writer) outLds[pBase + fm * 32 + fn * 2] = wv;
    }
  }

  __syncthreads();
  int pr = tid >> 4, pc = tid & 15;
  out[(size_t)(tm * 16 + pr) * 2048 + (tn * 16 + pc)] = outLds[tid];
}

// ---------------------------------------------------------------------------
extern "C" void kernel_launch(void* const* d_in, const int* in_sizes, int n_in,
                              void* d_out, int out_size, void* d_ws, size_t ws_size,
                              hipStream_t stream) {
  const float* img = (const float*)d_in[0];
  const float* cap = (const float*)d_in[1];
  float* out = (float*)d_out;

  char* ws = (char*)d_ws;
  unsigned short* Ahat = (unsigned short*)ws;                              // 4 MB, K-major
  unsigned short* Bhat = (unsigned short*)(ws + (size_t)4 * 1024 * 1024);  // 4 MB, K-major
  float* fa = (float*)(ws + (size_t)8 * 1024 * 1024);  // 2048*4 pairs (e,o)
  float* fb = fa + 2048 * 4 * 2;

  prep_kernel<<<1024, 256, 0, stream>>>(img, cap, Ahat, Bhat, fa, fb);
  sims_kernel<<<16384, 256, 0, stream>>>(Ahat, Bhat, fa, fb, out);
}